// Round 11
// baseline (1009.233 us; speedup 1.0000x reference)
//
#include <hip/hip_runtime.h>
#include <hip/hip_bf16.h>

#define B_ 4
#define N_ 4096
#define C_ 256
#define P_ 1024
#define S_ 64
#define HST 264   // H LDS k-stride (bf16 elems); 528B rows -> 2-way (free) frag reads
#define WKR 256   // worker blocks

typedef __attribute__((ext_vector_type(8))) short short8;
typedef __attribute__((ext_vector_type(4))) float f32x4;

__device__ __forceinline__ float rn_mul(float a, float b){ return __fmul_rn(a,b); }
__device__ __forceinline__ float rn_add(float a, float b){ return __fadd_rn(a,b); }
__device__ __forceinline__ float rn_sub(float a, float b){ return __fsub_rn(a,b); }

__device__ __forceinline__ unsigned short f2bf(float x){ // RNE f32->bf16
  union { float f; unsigned u; } v; v.f = x;
  unsigned r = v.u + 0x7fffu + ((v.u >> 16) & 1u);
  return (unsigned short)(r >> 16);
}

// v_max with a DPP-permuted copy; OOB/disabled lanes contribute 0 (safe: dists >= 0)
#define DPPMAX(m, ctrl) \
  m = fmaxf(m, __int_as_float(__builtin_amdgcn_update_dpp(0, __float_as_int(m), ctrl, 0xF, 0xF, true)))

// One kernel, 260 blocks (all guaranteed co-resident at 3 blocks/CU):
//   blocks 0..3   : FPS (r9-exact core), publishes winner INDEX per iteration via
//                   relaxed agent atomic store to gWidx (memset -1 each call).
//   blocks 4..259 : worker w: 16 ftrans tiles + 1 wprep row -> release ftdone;
//                   then 16x { poll gWidx[p], wave0 query -> LDS, 1-pt MFMA mlp -> out }
//                   with p = (w&63) + 64k  (stride-64: post-fps tail = 1 unit/block).
__global__ __launch_bounds__(256) void fused_kernel(
    const float* __restrict__ xyz, const float* __restrict__ feat,
    const float* __restrict__ rot,
    const float* __restrict__ W1, const float* __restrict__ b1,
    const float* __restrict__ W2, const float* __restrict__ b2,
    float* __restrict__ out,
    unsigned short* __restrict__ featT,
    unsigned short* __restrict__ Wp1, unsigned short* __restrict__ Wp2,
    int* __restrict__ gWidx, int* __restrict__ ftdone)
{
  __shared__ __align__(16) char shm[49664];
  const int gid = blockIdx.x;
  const int t = threadIdx.x;

  if (gid < B_){
    // ---------------- FPS: one block/batch, 4 waves x 16 pts (r9-exact core) ----------------
    // Exact fp32 distance semantics (_rn chain, left-fold). First-occurrence argmax:
    // lane-local keep-first (strict >, ascending j) -> lowest lane of value-match ballot
    // (lanes own contiguous ascending ranges) -> ascending-wave keep-first scan.
    float*  xl    = (float*)shm;                          // 48 KB point store
    float4* cand  = (float4*)(shm + N_*3*4);              // [2][4] value+coords
    int*    candI = (int*)(shm + N_*3*4 + 8*16);          // [2][4] winner indices
    const int b = gid;
    const int lane = t & 63, w = t >> 6;                  // 4 waves
    const float* xb = xyz + (size_t)b*N_*3;
    {
      float4* dst = (float4*)xl; const float4* src = (const float4*)xb;
      for (int i = t; i < N_*3/4; i += 256) dst[i] = src[i];
    }
    __syncthreads();
    float px[16], py[16], pz[16], dist[16];
    {
      float buf[48];
      #pragma unroll
      for (int i=0;i<12;i++){
        const float4 v = *(const float4*)&xl[t*48 + i*4];
        buf[i*4+0]=v.x; buf[i*4+1]=v.y; buf[i*4+2]=v.z; buf[i*4+3]=v.w;
      }
      #pragma unroll
      for (int j=0;j<16;j++){
        px[j]=buf[j*3+0]; py[j]=buf[j*3+1]; pz[j]=buf[j*3+2];
        dist[j] = 1e10f;
      }
    }
    float cx = xl[0], cy = xl[1], cz = xl[2];             // farthest_0 = 0
    if (t == 0)
      __hip_atomic_store(&gWidx[b*P_ + 0], 0, __ATOMIC_RELAXED, __HIP_MEMORY_SCOPE_AGENT);
    for (int it=0; it<P_; ++it){
      float bestv = -1.f; int bestj = 0;
      #pragma unroll
      for (int j=0;j<16;j++){
        const float dx = rn_sub(px[j],cx), dy = rn_sub(py[j],cy), dz = rn_sub(pz[j],cz);
        const float d  = rn_add(rn_add(rn_mul(dx,dx), rn_mul(dy,dy)), rn_mul(dz,dz));
        const float nd = fminf(dist[j], d);
        dist[j] = nd;
        if (nd > bestv){ bestv = nd; bestj = j; }   // strict > keeps first (lowest j)
      }
      float m = bestv;
      DPPMAX(m, 0x111);  // row_shr:1
      DPPMAX(m, 0x112);  // row_shr:2
      DPPMAX(m, 0x114);  // row_shr:4
      DPPMAX(m, 0x118);  // row_shr:8
      DPPMAX(m, 0x142);  // row_bcast:15
      DPPMAX(m, 0x143);  // row_bcast:31
      const float ms = __int_as_float(__builtin_amdgcn_readlane(__float_as_int(m), 63));
      const unsigned long long bal = __ballot(bestv == ms);
      const int winlane = __ffsll((long long)bal) - 1;        // lowest lane = lowest index
      const int widx = __builtin_amdgcn_readlane(t*16 + bestj, winlane) & ~15;
      const int wj   = __builtin_amdgcn_readlane(bestj, winlane);
      const int pb = it & 1;                                   // double buffer (skew <= 1)
      if (lane == 0){
        const float* cp = xl + (size_t)(widx + wj)*3;
        cand[pb*4 + w] = make_float4(ms, cp[0], cp[1], cp[2]);
        candI[pb*4 + w] = widx + wj;
      }
      __syncthreads();
      // keep-first scan over 4 wave candidates (ascending wave id)
      const float4 c0 = cand[pb*4+0], c1 = cand[pb*4+1], c2 = cand[pb*4+2], c3 = cand[pb*4+3];
      const int i0 = candI[pb*4+0], i1 = candI[pb*4+1], i2 = candI[pb*4+2], i3 = candI[pb*4+3];
      float fv = c0.x; cx = c0.y; cy = c0.z; cz = c0.w; int fi = i0;
      if (c1.x > fv){ fv = c1.x; cx = c1.y; cy = c1.z; cz = c1.w; fi = i1; }
      if (c2.x > fv){ fv = c2.x; cx = c2.y; cy = c2.z; cz = c2.w; fi = i2; }
      if (c3.x > fv){ fv = c3.x; cx = c3.y; cy = c3.z; cz = c3.w; fi = i3; }
      if (t == 0 && it + 1 < P_)
        __hip_atomic_store(&gWidx[b*P_ + it + 1], fi, __ATOMIC_RELAXED, __HIP_MEMORY_SCOPE_AGENT);
    }
  } else {
    // ================= worker block =================
    const int wk = gid - B_;            // 0..255
    const int b  = wk >> 6;             // 64 workers per batch
    // ---- phase 1: feature transpose, 16 tiles ----
    {
      float (*tile)[33] = (float (*)[33])shm;
      const int tx = t & 31, ty = t >> 5;  // 32x8
      for (int i=0;i<16;i++){
        const int idx = wk*16 + i;
        const int nx = idx & 127, cyi = (idx >> 7) & 7, bz = idx >> 10;
        const int n0 = nx*32, c0 = cyi*32;
        #pragma unroll
        for (int j=0;j<4;j++)
          tile[ty + j*8][tx] = feat[((size_t)bz*C_ + (size_t)(c0+ty+j*8))*N_ + n0 + tx];
        __syncthreads();
        #pragma unroll
        for (int j=0;j<4;j++)
          featT[((size_t)bz*N_ + (size_t)(n0+ty+j*8))*C_ + c0 + tx] = f2bf(tile[tx][ty + j*8]);
        __syncthreads();
      }
    }
    // ---- wprep row o = wk ----
    {
      const int o = wk;
      Wp1[o*288 + t] = f2bf(W1[o*259 + 3 + t]);
      if (t < 32){
        float v = (t < 3) ? W1[o*259 + t] : 0.f;
        Wp1[o*288 + 256 + t] = f2bf(v);
      }
      Wp2[o*256 + t] = f2bf(W2[o*256 + t]);
    }
    __threadfence();                     // write back dirty L2 lines (featT/Wp)
    __syncthreads();
    if (t == 0)
      __hip_atomic_fetch_add(ftdone, 1, __ATOMIC_RELEASE, __HIP_MEMORY_SCOPE_AGENT);

    // ---- phase 2 LDS layout (after Hlds) ----
    unsigned short* Hlds = (unsigned short*)shm;                       // 33792 B
    int*            sI   = (int*)(shm + 64*HST*2);                     // 256 B
    unsigned short* rotP = (unsigned short*)(shm + 64*HST*2 + 256);    // 1024 B
    int*            sWi  = (int*)(shm + 64*HST*2 + 256 + 1024);        // 4 B

    const int lane = t & 63, wv = t >> 6;
    const int l15 = lane & 15, q = lane >> 4;
    bool ftOK = false;

    for (int k=0;k<16;k++){
      const int p = (wk & 63) + 64*k;
      const int bp = b*P_ + p;
      // ---- wait for fps to publish centroid index p ----
      if (t == 0){
        int wi;
        while ((wi = __hip_atomic_load(&gWidx[bp], __ATOMIC_RELAXED, __HIP_MEMORY_SCOPE_AGENT)) == -1)
          __builtin_amdgcn_s_sleep(32);
        *sWi = wi;
      }
      __syncthreads();
      const int wi = *sWi;
      // ---- cylinder query (wave 0), outputs to LDS ----
      if (wv == 0){
        const float* xb = xyz + (size_t)b*N_*3;
        const float* r9 = rot + (size_t)bp*9;
        const float R0=r9[0],R1=r9[1],R2=r9[2],R3=r9[3],R4=r9[4],R5=r9[5],R6=r9[6],R7=r9[7],R8=r9[8];
        const float nx = xb[wi*3+0], ny = xb[wi*3+1], nz = xb[wi*3+2];
        const float thr = R2;   // replicate the reference's r2-shadowing bug
        int filled = 0;
        float p0r0=0.f, p0r1=0.f, p0r2=0.f;
        for (int base = 0; base < N_; base += 64){
          const int n = base + lane;
          const float dx = rn_sub(xb[n*3+0], nx);
          const float dy = rn_sub(xb[n*3+1], ny);
          const float dz = rn_sub(xb[n*3+2], nz);
          const float r0 = rn_add(rn_add(rn_mul(dx,R0), rn_mul(dy,R3)), rn_mul(dz,R6));
          const float r1 = rn_add(rn_add(rn_mul(dx,R1), rn_mul(dy,R4)), rn_mul(dz,R7));
          const float r2 = rn_add(rn_add(rn_mul(dx,R2), rn_mul(dy,R5)), rn_mul(dz,R8));
          if (base == 0){
            p0r0 = __shfl(r0, 0, 64); p0r1 = __shfl(r1, 0, 64); p0r2 = __shfl(r2, 0, 64);
          }
          const float d2 = rn_add(rn_mul(r1,r1), rn_mul(r2,r2));
          const bool mq = (d2 < thr) & (r0 > -0.02f) & (r0 < 0.04f);
          const unsigned long long bal = __ballot(mq);
          const int before = (int)__popcll(bal & ((1ull << lane) - 1ull));
          const int slot = filled + before;
          if (mq && slot < S_){
            sI[slot] = n;
            uint4 u;
            u.x = (unsigned)f2bf(r0) | ((unsigned)f2bf(r1) << 16);
            u.y = (unsigned)f2bf(r2);
            u.z = 0u; u.w = 0u;
            *(uint4*)&rotP[slot*8] = u;
          }
          filled += (int)__popcll(bal);
          if (filled >= S_) break;
        }
        if (filled < S_){
          const int slot = filled + lane;
          if (slot < S_){
            sI[slot] = 0;
            uint4 u;
            u.x = (unsigned)f2bf(p0r0) | ((unsigned)f2bf(p0r1) << 16);
            u.y = (unsigned)f2bf(p0r2);
            u.z = 0u; u.w = 0u;
            *(uint4*)&rotP[slot*8] = u;
          }
        }
      }
      __syncthreads();
      // ---- gate first mlp on featT/Wp completion (once per block) ----
      if (!ftOK){
        if (t == 0){
          while (__hip_atomic_load(ftdone, __ATOMIC_RELAXED, __HIP_MEMORY_SCOPE_AGENT) != WKR)
            __builtin_amdgcn_s_sleep(32);
        }
        __syncthreads();
        __builtin_amdgcn_fence(__ATOMIC_ACQUIRE, "agent");   // invalidate stale lines
        ftOK = true;
      }
      // ---- 1-pt MFMA mlp (bit-identical accumulation order to proven 2-pt kernel) ----
      {
        unsigned rowOff[4];
        #pragma unroll
        for (int st=0; st<4; ++st){
          const int s = st*16 + l15;
          const int row = sI[s];
          rowOff[st] = (unsigned)(((b*N_ + row)*C_ + q*8) * 2);
        }
        const char* fbase = (const char*)featT;
        f32x4 acc[4][4];
        #pragma unroll
        for (int at=0; at<4; ++at){
          const float4 bv = *(const float4*)(b1 + wv*64 + at*16 + q*4);
          #pragma unroll
          for (int st=0; st<4; ++st){
            acc[at][st][0]=bv.x; acc[at][st][1]=bv.y; acc[at][st][2]=bv.z; acc[at][st][3]=bv.w;
          }
        }
        const unsigned short* wb1 = Wp1 + (size_t)(wv*64 + l15)*288 + q*8;
        #pragma unroll
        for (int ks=0; ks<8; ++ks){
          short8 a[4], x[4];
          #pragma unroll
          for (int at=0; at<4; ++at) a[at] = *(const short8*)(wb1 + at*16*288 + ks*32);
          #pragma unroll
          for (int st=0; st<4; ++st) x[st] = *(const short8*)(fbase + rowOff[st] + ks*64);
          #pragma unroll
          for (int at=0; at<4; ++at)
            #pragma unroll
            for (int st=0; st<4; ++st)
              acc[at][st] = __builtin_amdgcn_mfma_f32_16x16x32_bf16(a[at], x[st], acc[at][st], 0,0,0);
        }
        { // K-step 8: rot fragments from LDS, rest zero
          short8 a[4], x[4];
          #pragma unroll
          for (int at=0; at<4; ++at) a[at] = *(const short8*)(wb1 + at*16*288 + 8*32);
          #pragma unroll
          for (int st=0; st<4; ++st){
            short8 v = (short8){0,0,0,0,0,0,0,0};
            if (q == 0) v = *(const short8*)&rotP[(st*16 + l15)*8];
            x[st] = v;
          }
          #pragma unroll
          for (int at=0; at<4; ++at)
            #pragma unroll
            for (int st=0; st<4; ++st)
              acc[at][st] = __builtin_amdgcn_mfma_f32_16x16x32_bf16(a[at], x[st], acc[at][st], 0,0,0);
        }
        // relu -> bf16 -> Hlds[s][o]
        #pragma unroll
        for (int at=0; at<4; ++at)
          #pragma unroll
          for (int st=0; st<4; ++st){
            const int s = st*16 + l15;
            const int o = wv*64 + at*16 + q*4;
            const unsigned h0 = f2bf(fmaxf(acc[at][st][0], 0.f));
            const unsigned h1 = f2bf(fmaxf(acc[at][st][1], 0.f));
            const unsigned h2 = f2bf(fmaxf(acc[at][st][2], 0.f));
            const unsigned h3 = f2bf(fmaxf(acc[at][st][3], 0.f));
            uint2 u; u.x = h0 | (h1 << 16); u.y = h2 | (h3 << 16);
            *(uint2*)&Hlds[s*HST + o] = u;
          }
        __syncthreads();
        // layer 2
        #pragma unroll
        for (int at=0; at<4; ++at){
          const float4 bv = *(const float4*)(b2 + wv*64 + at*16 + q*4);
          #pragma unroll
          for (int st=0; st<4; ++st){
            acc[at][st][0]=bv.x; acc[at][st][1]=bv.y; acc[at][st][2]=bv.z; acc[at][st][3]=bv.w;
          }
        }
        const unsigned short* wb2 = Wp2 + (size_t)(wv*64 + l15)*256 + q*8;
        #pragma unroll
        for (int ks=0; ks<8; ++ks){
          short8 a[4], h[4];
          #pragma unroll
          for (int at=0; at<4; ++at) a[at] = *(const short8*)(wb2 + at*16*256 + ks*32);
          #pragma unroll
          for (int st=0; st<4; ++st)
            h[st] = *(const short8*)&Hlds[(st*16 + l15)*HST + ks*32 + q*8];
          #pragma unroll
          for (int at=0; at<4; ++at)
            #pragma unroll
            for (int st=0; st<4; ++st)
              acc[at][st] = __builtin_amdgcn_mfma_f32_16x16x32_bf16(a[at], h[st], acc[at][st], 0,0,0);
        }
        // max over s, relu, store
        #pragma unroll
        for (int at=0; at<4; ++at){
          #pragma unroll
          for (int r=0; r<4; ++r){
            float mm = fmaxf(fmaxf(acc[at][0][r], acc[at][1][r]),
                             fmaxf(acc[at][2][r], acc[at][3][r]));
            mm = fmaxf(mm, __shfl_xor(mm, 1, 64));
            mm = fmaxf(mm, __shfl_xor(mm, 2, 64));
            mm = fmaxf(mm, __shfl_xor(mm, 4, 64));
            mm = fmaxf(mm, __shfl_xor(mm, 8, 64));
            mm = fmaxf(mm, 0.f);
            if (l15 == 0){
              const int o = wv*64 + at*16 + q*4 + r;
              out[((size_t)b*256 + o)*P_ + p] = mm;
            }
          }
        }
      }
      __syncthreads();   // before next k reuses sI/rotP/Hlds
    }
  }
}

extern "C" void kernel_launch(void* const* d_in, const int* in_sizes, int n_in,
                              void* d_out, int out_size, void* d_ws, size_t ws_size,
                              hipStream_t stream)
{
  const float* xyz  = (const float*)d_in[0];
  const float* feat = (const float*)d_in[1];
  const float* rot  = (const float*)d_in[2];
  const float* W1   = (const float*)d_in[3];
  const float* b1   = (const float*)d_in[4];
  const float* W2   = (const float*)d_in[5];
  const float* b2   = (const float*)d_in[6];
  float* out = (float*)d_out;

  char* ws = (char*)d_ws;
  unsigned short* featT = (unsigned short*)(ws);
  size_t off = (size_t)B_*N_*C_*2;                                   // 8.39 MB
  unsigned short* Wp1 = (unsigned short*)(ws + off); off += (size_t)256*288*2;
  unsigned short* Wp2 = (unsigned short*)(ws + off); off += (size_t)256*256*2;
  int* gWidx  = (int*)(ws + off); off += (size_t)B_*P_*4;            // 16 KB
  int* ftdone = (int*)(ws + off); off += 16;
  (void)ws_size; (void)in_sizes; (void)n_in; (void)out_size;

  hipMemsetAsync(gWidx, 0xFF, (size_t)B_*P_*4, stream);   // -1 sentinels (deterministic)
  hipMemsetAsync(ftdone, 0, 4, stream);
  hipLaunchKernelGGL(fused_kernel, dim3(B_ + WKR), dim3(256), 0, stream,
                     xyz, feat, rot, W1, b1, W2, b2, out,
                     featT, Wp1, Wp2, gWidx, ftdone);
}